// Round 9
// baseline (539.051 us; speedup 1.0000x reference)
//
#include <hip/hip_runtime.h>

// 3x3 PCF soft-shadow — global 2D tile binning + LDS-staged taps + XCD-affine batches.
// vis[i] = (1/9) * sum_{ii,jj} sigmoid((zbuf[b, clip(y+ii), clip(x+jj)] - (depth_z[i]-BIAS)) * 1000)
//
// R8 measured: traffic is the wall, but not streaming — WRITE_SIZE 297 MB for a
// 32 MB output + ~200 MB write-allocate refetch: all 8 XCDs write 4B fragments
// into the SAME out lines (bins mix ils over the whole batch; batch = bin>>10
// spread every batch over all XCDs; per-XCD L2s are not coherent -> private
// partial copies, eviction storm, random 64B HBM traffic).
// Fix: batch == XCD. blockIdx round-robins XCDs mod 8, so batch = blockIdx&7
// pins each batch's depth/out/zbuf/slabs to ONE XCD's L2:
//   - out lines collect all 16 stores in one L2 -> ~32 MB written once
//   - depth lines fetched once, then L2/L3 hits
//   P1: bin 8.4M px into (batch, 64x64 tile); rec = il(20)|xl(6)|yl(6).
//   P2: stage 66x66 tile+halo once (coalesced), 9 taps from LDS; remaining
//       divergent traffic: 1 depth read + 1 out write per record, XCD-local.

#define SHARPNESS 1000.0f
#define BIAS 0.008f
#define S2LOG2E 1442.6950408889634f    // 1000 * log2(e)

#define S_IMG     2048
#define NBATCH    8
#define HWK       (1 << 20)
#define TSH       6                    // 64x64 tiles
#define TPS       (S_IMG >> TSH)       // 32 tiles per side
#define BPB       (TPS * TPS)          // 1024 bins per batch
#define NBINS     (NBATCH * BPB)       // 8192
#define SLAB_CAP  1280                 // mean 1024, sigma 32 -> +8 sigma
#define RPTMAX    5                    // ceil(SLAB_CAP / 256)
#define STW       66                   // staged tile width (64 + halo)
#define REC_BYTES ((size_t)NBINS * SLAB_CAP * 4ull)   // 41.9 MB
#define WS_NEED   (REC_BYTES + (size_t)NBINS * 4ull)

#define P1_BLOCKS 512                  // 1024 thr, 16384 px each
#define PXB       16384

typedef int i4v __attribute__((ext_vector_type(4)));

__device__ __forceinline__ float sigf(float bb, float a) {
    const float t = (a - bb) * S2LOG2E;            // keep 2-op form: bit-stable
    return __builtin_amdgcn_rcpf(1.0f + exp2f(t));
}

// ---------------- Pass 1: global (batch, tile) binning, XCD-affine ----------------
__global__ __launch_bounds__(1024, 8) void p1_bin(
    const int* __restrict__ xy_raw,
    unsigned* __restrict__ recs, unsigned* __restrict__ gcur)
{
    __shared__ unsigned cnt[BPB];
    __shared__ unsigned cur[BPB];
    const int blk   = blockIdx.x;              // 512 blocks
    const int tid   = threadIdx.x;
    const int batch = blk & 7;                 // batch == XCD (blockIdx%8)
    const int sub   = blk >> 3;                // 64 sub-blocks per batch
    const int ilb   = sub * PXB;               // il base within batch
    if (tid < BPB) cnt[tid] = 0;
    __syncthreads();

    // pass A: load 16 px (8 x 16B), pack coords in VGPRs, LDS histogram
    unsigned pk[16];
    const i4v* xy4 = (const i4v*)xy_raw + ((size_t)batch * HWK + ilb) / 2;
#pragma unroll
    for (int j = 0; j < 8; ++j) {
        const i4v q = __builtin_nontemporal_load(&xy4[j * 1024 + tid]);
        pk[2 * j]     = (unsigned)q.x | ((unsigned)q.y << 11);
        pk[2 * j + 1] = (unsigned)q.z | ((unsigned)q.w << 11);
        atomicAdd(&cnt[((q.y >> TSH) << 5) | (q.x >> TSH)], 1u);
        atomicAdd(&cnt[((q.w >> TSH) << 5) | (q.z >> TSH)], 1u);
    }
    __syncthreads();

    // allocate this block's run in each bin's slab (absolute position base)
    if (tid < BPB) cur[tid] = atomicAdd(&gcur[batch * BPB + tid], cnt[tid]);
    __syncthreads();

    // pass B: LDS-ranked scatter, ~64B runs per (block, bin), XCD-local slabs
#pragma unroll
    for (int j = 0; j < 16; ++j) {
        const int x  = (int)(pk[j] & 0x7FFu);
        const int y  = (int)(pk[j] >> 11);
        const int bn = ((y >> TSH) << 5) | (x >> TSH);
        const unsigned pos = atomicAdd(&cur[bn], 1u);
        const int il = ilb + 2 * ((j >> 1) * 1024 + tid) + (j & 1);
        const unsigned rec = (unsigned)il
                           | ((unsigned)(x & 63) << 20)
                           | ((unsigned)(y & 63) << 26);
        if (pos < SLAB_CAP)
            recs[(size_t)(batch * BPB + bn) * SLAB_CAP + pos] = rec;
    }
}

// ---------------- Pass 2: LDS-staged tile, unrolled eval, XCD-affine ----------------
__global__ __launch_bounds__(256, 8) void p2_pcf(
    const float* __restrict__ zbuf, const float* __restrict__ depth,
    const unsigned* __restrict__ recs, const unsigned* __restrict__ gcur,
    float* __restrict__ out)
{
    __shared__ float zt[STW * STW];            // 17.4 KB -> 8 blocks/CU
    const int g     = blockIdx.x;              // 8192
    const int batch = g & 7;                   // batch == XCD (blockIdx%8)
    const int t     = g >> 3;                  // tile id within batch
    const int bin   = batch * BPB + t;
    const int tx    = t & (TPS - 1);
    const int ty    = t >> 5;
    const int tid   = threadIdx.x;
    const float* zb = zbuf + (size_t)batch * ((size_t)S_IMG * S_IMG);
    const int x0 = tx * 64 - 1, y0 = ty * 64 - 1;

    const int n  = min((int)gcur[bin], SLAB_CAP);
    const int nc = n - 1;
    const unsigned* slab = recs + (size_t)bin * SLAB_CAP;
    const float* dpb = depth + (size_t)batch * HWK;
    float*       opb = out + (size_t)batch * HWK;

    // ---- load records + depths EARLY; latency hides under staging+barrier ----
    unsigned R[RPTMAX]; int IL[RPTMAX]; float D[RPTMAX];
#pragma unroll
    for (int j = 0; j < RPTMAX; ++j)
        R[j] = slab[min(j * 256 + tid, nc)];   // clamped: dummy work, guarded store
#pragma unroll
    for (int j = 0; j < RPTMAX; ++j)
        IL[j] = (int)(R[j] & 0xFFFFFu);
#pragma unroll
    for (int j = 0; j < RPTMAX; ++j)
        D[j] = dpb[IL[j]];                     // XCD-local lines

    // ---- stage 66x66 tile + clamped halo, coalesced; zbuf read ONCE ----
    for (int i = tid; i < STW * STW; i += 256) {
        const int r  = i / STW;
        const int c  = i - r * STW;
        const int gy = min(max(y0 + r, 0), S_IMG - 1);
        const int gx = min(max(x0 + c, 0), S_IMG - 1);
        zt[i] = zb[(size_t)gy * S_IMG + gx];
    }
    __syncthreads();

    // ---- straight-line unrolled eval: independent records, static indices ----
#pragma unroll
    for (int j = 0; j < RPTMAX; ++j) {
        const float a  = D[j] - BIAS;
        const int   xl = (int)((R[j] >> 20) & 63u);
        const int   yl = (int)(R[j] >> 26);
        const float* p = zt + yl * STW + xl;   // pixel at (yl+1, xl+1); taps 0..2
        const float vis =
              sigf(p[0],           a) + sigf(p[1],           a) + sigf(p[2],           a)
            + sigf(p[STW],         a) + sigf(p[STW + 1],     a) + sigf(p[STW + 2],     a)
            + sigf(p[2 * STW],     a) + sigf(p[2 * STW + 1], a) + sigf(p[2 * STW + 2], a);
        if (j * 256 + tid <= nc)
            opb[IL[j]] = vis * (1.0f / 9.0f);  // XCD-local: line collects all
    }                                          // 16 stores in ONE L2 copy
}

// ---------------- fallback: direct kernel ----------------
__global__ __launch_bounds__(256) void pcf_shadow_generic(
    const float* __restrict__ zbuf, const float* __restrict__ depth_z,
    const int2* __restrict__ xy, const int* __restrict__ image_size_p,
    float* __restrict__ out, int total, int zbuf_elems)
{
    const int i = blockIdx.x * blockDim.x + threadIdx.x;
    if (i >= total) return;
    const int S  = *image_size_p;
    const int SS = S * S;
    const int N  = zbuf_elems / SS;
    const int hwk = total / N;
    const int b   = i / hwk;
    const float a = depth_z[i] - BIAS;
    const int2 p  = xy[i];
    const float* base = zbuf + (size_t)b * (size_t)SS;
    float vis = 0.0f;
#pragma unroll
    for (int ii = -1; ii <= 1; ++ii) {
        const int yi = min(max(p.y + ii, 0), S - 1);
        const float* row = base + (size_t)yi * (size_t)S;
#pragma unroll
        for (int jj = -1; jj <= 1; ++jj) {
            const int xi = min(max(p.x + jj, 0), S - 1);
            vis += 1.0f / (1.0f + __expf((a - row[xi]) * SHARPNESS));
        }
    }
    out[i] = vis * (1.0f / 9.0f);
}

extern "C" void kernel_launch(void* const* d_in, const int* in_sizes, int n_in,
                              void* d_out, int out_size, void* d_ws, size_t ws_size,
                              hipStream_t stream) {
    const float* zbuf     = (const float*)d_in[0];
    const float* depth_z  = (const float*)d_in[1];
    const int*   xy_raw   = (const int*)d_in[2];
    const int*   img_size = (const int*)d_in[3];
    float*       out      = (float*)d_out;

    const int zbuf_elems = in_sizes[0];   // N*S*S
    const int total      = in_sizes[1];   // N*H*W*K

    if (zbuf_elems == NBATCH * S_IMG * S_IMG && total == NBATCH * HWK &&
        ws_size >= WS_NEED) {
        unsigned* recs = (unsigned*)d_ws;
        unsigned* gcur = (unsigned*)((char*)d_ws + REC_BYTES);
        hipMemsetAsync(gcur, 0, (size_t)NBINS * 4ull, stream);
        p1_bin<<<P1_BLOCKS, 1024, 0, stream>>>(xy_raw, recs, gcur);
        p2_pcf<<<NBINS, 256, 0, stream>>>(zbuf, depth_z, recs, gcur, out);
    } else {
        const int block = 256;
        const int grid  = (total + block - 1) / block;
        pcf_shadow_generic<<<grid, block, 0, stream>>>(zbuf, depth_z, (const int2*)xy_raw,
                                                       img_size, out, total, zbuf_elems);
    }
}

// Round 10
// 432.817 us; speedup vs baseline: 1.2454x; 1.2454x over previous
//
#include <hip/hip_runtime.h>

// 3x3 PCF soft-shadow — 3-pass: bin(+depth,+inverse-perm) / tile-LDS eval / coalesced de-permute.
// vis[i] = (1/9) * sum_{ii,jj} sigmoid((zbuf[b, clip(y+ii), clip(x+jj)] - (depth_z[i]-BIAS)) * 1000)
//
// R0-R9 law: dur ~= hbm_bytes / 3.3 TB/s (random-64B-line HBM ceiling). The
// residual inflation is the scattered 4B out-store (32 MB -> ~300 MB partial
// writebacks + ~200 MB write-allocate refetch) and the depth gather (~160 MB).
// This version has NO scattered HBM access anywhere:
//   P1: read xy+depth coalesced; 8B record (xl6|yl6, depth f32) into
//       (batch, 64x64 tile) bins; ALSO write pidx[il] = slab slot (coalesced)
//       = the inverse permutation. Overflow -> sentinel.
//   P2: per-bin 66x66 LDS tile staging; records carry depth; vis overwrites
//       the record's depth word IN PLACE (line L2-resident -> full-line dirty
//       writeback, no allocate refetch). Zero divergent global access.
//   P3: out[il] = slab[pidx[il]].vis — coalesced read+write; the vis gather
//       hits the L3-resident slab P2 just wrote. Sentinel lanes recompute.
// Host tiles rounds (8/4/2 batches) to fit ws; generic fallback otherwise.

#define SHARPNESS 1000.0f
#define BIAS 0.008f
#define S2LOG2E 1442.6950408889634f    // 1000 * log2(e)

#define S_IMG   2048
#define NBATCH  8
#define HWK     (1 << 20)
#define TSH     6                      // 64x64 tiles
#define TPS     32
#define BPB     (TPS * TPS)            // 1024 bins per batch
#define CAP     1280                   // mean 1024, sigma 32 -> +8 sigma
#define STW     66                     // staged tile width (64 + halo)
#define PXB     16384                  // pixels per P1 block
#define SENT    0xFFFFFFFFu

typedef int      i4v __attribute__((ext_vector_type(4)));
typedef float    f2v __attribute__((ext_vector_type(2)));
typedef float    f4v __attribute__((ext_vector_type(4)));
typedef unsigned u2v __attribute__((ext_vector_type(2)));

__device__ __forceinline__ float sigf(float bb, float a) {
    const float t = (a - bb) * S2LOG2E;            // keep 2-op form: bit-stable
    return __builtin_amdgcn_rcpf(1.0f + exp2f(t));
}

// ---------------- Pass 1: bin (records carry depth), emit inverse perm ----------------
__global__ __launch_bounds__(1024, 2) void p1_bin(
    const int* __restrict__ xy_raw, const float* __restrict__ depth,
    u2v* __restrict__ slab, unsigned* __restrict__ pidx,
    unsigned* __restrict__ gcur, int b0)
{
    __shared__ unsigned cnt[BPB];
    __shared__ unsigned cur[BPB];
    const int blk = blockIdx.x;
    const int bl  = blk >> 6;                      // round-local batch
    const int sub = blk & 63;
    const int tid = threadIdx.x;
    cnt[tid] = 0;
    __syncthreads();

    const size_t pb_g = ((size_t)(b0 + bl)) * HWK + (size_t)sub * PXB;
    const i4v* xq = (const i4v*)xy_raw + pb_g / 2;     // 2 px per 16B
    const f2v* dq = (const f2v*)depth  + pb_g / 2;     // 2 px per 8B

    unsigned pk[16]; float dd[16];
#pragma unroll
    for (int j = 0; j < 8; ++j) {
        const i4v q = __builtin_nontemporal_load(&xq[j * 1024 + tid]);
        const f2v d = __builtin_nontemporal_load(&dq[j * 1024 + tid]);
        pk[2 * j]     = (unsigned)q.x | ((unsigned)q.y << 11);
        pk[2 * j + 1] = (unsigned)q.z | ((unsigned)q.w << 11);
        dd[2 * j] = d.x; dd[2 * j + 1] = d.y;
        atomicAdd(&cnt[((q.y >> TSH) << 5) | (q.x >> TSH)], 1u);
        atomicAdd(&cnt[((q.w >> TSH) << 5) | (q.z >> TSH)], 1u);
    }
    __syncthreads();
    cur[tid] = atomicAdd(&gcur[bl * BPB + tid], cnt[tid]);
    __syncthreads();

    const size_t pb_l = (size_t)bl * HWK + (size_t)sub * PXB;  // round-local px base
    u2v* px2 = (u2v*)pidx + pb_l / 2;
#pragma unroll
    for (int j = 0; j < 8; ++j) {
        u2v pi;
#pragma unroll
        for (int e = 0; e < 2; ++e) {
            const unsigned w = pk[2 * j + e];
            const int x = (int)(w & 0x7FFu), y = (int)(w >> 11);
            const int bn = ((y >> TSH) << 5) | (x >> TSH);
            const unsigned pos = atomicAdd(&cur[bn], 1u);
            unsigned v = SENT;
            if (pos < CAP) {
                const unsigned slot = (unsigned)(bl * BPB + bn) * CAP + pos;
                u2v r;
                r.x = (unsigned)(x & 63) | ((unsigned)(y & 63) << 6);
                r.y = __float_as_uint(dd[2 * j + e]);
                slab[slot] = r;
                v = slot;
            }
            if (e == 0) pi.x = v; else pi.y = v;
        }
        px2[j * 1024 + tid] = pi;                  // coalesced inverse perm
    }
}

// ---------------- Pass 2: LDS tile, depth from record, vis in place ----------------
__global__ __launch_bounds__(256, 8) void p2_tile(
    const float* __restrict__ zbuf, u2v* __restrict__ slab,
    const unsigned* __restrict__ gcur, int b0)
{
    __shared__ float zt[STW * STW];                // 17.4 KB -> 8 blocks/CU
    const int gb  = blockIdx.x;                    // round-local bin
    const int tid = threadIdx.x;
    const int bl  = gb >> 10;
    const int t   = gb & (BPB - 1);
    const int tx  = t & 31, ty = t >> 5;
    const float* zb = zbuf + (size_t)(b0 + bl) * ((size_t)S_IMG * S_IMG);
    const int x0 = tx * 64 - 1, y0 = ty * 64 - 1;

    const int n   = min((int)gcur[gb], CAP);
    const int nc  = n - 1;
    const int ncc = max(nc, 0);
    u2v* sl = slab + (size_t)gb * CAP;

    // preload records early; latency hides under staging + barrier
    u2v Rc[5];
#pragma unroll
    for (int j = 0; j < 5; ++j)
        Rc[j] = sl[min(j * 256 + tid, ncc)];

    for (int i = tid; i < STW * STW; i += 256) {
        const int r  = i / STW, c = i - r * STW;
        const int gy = min(max(y0 + r, 0), S_IMG - 1);
        const int gx = min(max(x0 + c, 0), S_IMG - 1);
        zt[i] = zb[(size_t)gy * S_IMG + gx];       // zbuf read ONCE, coalesced
    }
    __syncthreads();

    float* slf = (float*)sl;
#pragma unroll
    for (int j = 0; j < 5; ++j) {
        const unsigned w = Rc[j].x;
        const float a  = __uint_as_float(Rc[j].y) - BIAS;
        const float* p = zt + (int)((w >> 6) & 63u) * STW + (int)(w & 63u);
        const float vis =
              sigf(p[0],           a) + sigf(p[1],           a) + sigf(p[2],           a)
            + sigf(p[STW],         a) + sigf(p[STW + 1],     a) + sigf(p[STW + 2],     a)
            + sigf(p[2 * STW],     a) + sigf(p[2 * STW + 1], a) + sigf(p[2 * STW + 2], a);
        const int k = j * 256 + tid;
        if (k <= nc) slf[2 * k + 1] = vis * (1.0f / 9.0f);  // in-place over depth:
    }                                              // line already in L2, no allocate
}

// ---------------- Pass 3: coalesced de-permute (gather hits L3-warm slab) ----------------
__global__ __launch_bounds__(256) void p3_out(
    const unsigned* __restrict__ pidx, const float* __restrict__ slabf,
    float* __restrict__ out,
    const float* __restrict__ zbuf, const float* __restrict__ depth,
    const int* __restrict__ xy_raw, int b0)
{
    const int tid = threadIdx.x;
    const i4v* px4 = (const i4v*)pidx;
    const size_t gbase = (size_t)blockIdx.x * 1024;  // i4v groups; 4096 px/block

    i4v P[4];
#pragma unroll
    for (int j = 0; j < 4; ++j)
        P[j] = __builtin_nontemporal_load(&px4[gbase + j * 256 + tid]);

    f4v V[4];
#pragma unroll
    for (int j = 0; j < 4; ++j) {
#pragma unroll
        for (int e = 0; e < 4; ++e) {
            const unsigned pi = (unsigned)P[j][e];
            float v;
            if (pi != SENT) {
                v = slabf[2 * (size_t)pi + 1];     // L3-resident vis
            } else {                               // overflow: recompute (≈never)
                const size_t il = (size_t)b0 * HWK + (gbase + j * 256 + tid) * 4 + e;
                const int batch = (int)(il >> 20);
                const float a = depth[il] - BIAS;
                const int x = xy_raw[2 * il], y = xy_raw[2 * il + 1];
                const float* zbb = zbuf + (size_t)batch * ((size_t)S_IMG * S_IMG);
                float vv = 0.0f;
                for (int ii = -1; ii <= 1; ++ii) {
                    const int yi = min(max(y + ii, 0), S_IMG - 1);
                    const float* row = zbb + (size_t)yi * S_IMG;
                    for (int jj = -1; jj <= 1; ++jj)
                        vv += sigf(row[min(max(x + jj, 0), S_IMG - 1)], a);
                }
                v = vv * (1.0f / 9.0f);
            }
            V[j][e] = v;
        }
    }

    f4v* o4 = (f4v*)(out + (size_t)b0 * HWK);
#pragma unroll
    for (int j = 0; j < 4; ++j)
        __builtin_nontemporal_store(V[j], &o4[gbase + j * 256 + tid]);
}

// ---------------- fallback: direct kernel ----------------
__global__ __launch_bounds__(256) void pcf_shadow_generic(
    const float* __restrict__ zbuf, const float* __restrict__ depth_z,
    const int2* __restrict__ xy, const int* __restrict__ image_size_p,
    float* __restrict__ out, int total, int zbuf_elems)
{
    const int i = blockIdx.x * blockDim.x + threadIdx.x;
    if (i >= total) return;
    const int S  = *image_size_p;
    const int SS = S * S;
    const int N  = zbuf_elems / SS;
    const int hwk = total / N;
    const int b   = i / hwk;
    const float a = depth_z[i] - BIAS;
    const int2 p  = xy[i];
    const float* base = zbuf + (size_t)b * (size_t)SS;
    float vis = 0.0f;
#pragma unroll
    for (int ii = -1; ii <= 1; ++ii) {
        const int yi = min(max(p.y + ii, 0), S - 1);
        const float* row = base + (size_t)yi * (size_t)S;
#pragma unroll
        for (int jj = -1; jj <= 1; ++jj) {
            const int xi = min(max(p.x + jj, 0), S - 1);
            vis += 1.0f / (1.0f + __expf((a - row[xi]) * SHARPNESS));
        }
    }
    out[i] = vis * (1.0f / 9.0f);
}

extern "C" void kernel_launch(void* const* d_in, const int* in_sizes, int n_in,
                              void* d_out, int out_size, void* d_ws, size_t ws_size,
                              hipStream_t stream) {
    const float* zbuf     = (const float*)d_in[0];
    const float* depth_z  = (const float*)d_in[1];
    const int*   xy_raw   = (const int*)d_in[2];
    const int*   img_size = (const int*)d_in[3];
    float*       out      = (float*)d_out;

    const int zbuf_elems = in_sizes[0];   // N*S*S
    const int total      = in_sizes[1];   // N*H*W*K

    if (zbuf_elems == NBATCH * S_IMG * S_IMG && total == NBATCH * HWK) {
        // per-batch workspace: slab 8B*BPB*CAP + pidx 4B*HWK + gcur 4B*BPB
        const size_t per_b = (size_t)BPB * CAP * 8ull + (size_t)HWK * 4ull
                           + (size_t)BPB * 4ull;                  // ~14.7 MB
        int nb = 0;
        if      (ws_size >= 8 * per_b) nb = 8;    // 117.5 MB
        else if (ws_size >= 4 * per_b) nb = 4;    //  58.7 MB
        else if (ws_size >= 2 * per_b) nb = 2;    //  29.4 MB (<= proven 50.3)
        else if (ws_size >= 1 * per_b) nb = 1;

        if (nb) {
            const size_t slab_b = (size_t)nb * BPB * CAP * 8ull;
            const size_t pidx_b = (size_t)nb * HWK * 4ull;
            u2v*      slab = (u2v*)d_ws;
            unsigned* pidx = (unsigned*)((char*)d_ws + slab_b);
            unsigned* gcur = (unsigned*)((char*)d_ws + slab_b + pidx_b);
            for (int b0 = 0; b0 < NBATCH; b0 += nb) {
                hipMemsetAsync(gcur, 0, (size_t)nb * BPB * 4ull, stream);
                p1_bin<<<nb * 64,  1024, 0, stream>>>(xy_raw, depth_z, slab, pidx, gcur, b0);
                p2_tile<<<nb * BPB, 256, 0, stream>>>(zbuf, slab, gcur, b0);
                p3_out<<<nb * 256,  256, 0, stream>>>(pidx, (const float*)slab, out,
                                                      zbuf, depth_z, xy_raw, b0);
            }
            return;
        }
    }
    const int block = 256;
    const int grid  = (total + block - 1) / block;
    pcf_shadow_generic<<<grid, block, 0, stream>>>(zbuf, depth_z, (const int2*)xy_raw,
                                                   img_size, out, total, zbuf_elems);
}

// Round 11
// 394.406 us; speedup vs baseline: 1.3667x; 1.0974x over previous
//
#include <hip/hip_runtime.h>

// 3x3 PCF soft-shadow — 3-pass, ALL HBM stores full-line/one-shot.
// vis[i] = (1/9) * sum_{ii,jj} sigmoid((zbuf[b, clip(y+ii), clip(x+jj)] - (depth_z[i]-BIAS)) * 1000)
//
// R10 measured: p1's slab scatter = 277 MB HBM writes for ~100 MB logical
// (partial-dirty 64B lines evicted repeatedly, cross-XCD). R0-R10 law:
// dur ~= hbm_bytes / rate, rate 3.3 TB/s random vs 6.3 streaming.
// This version makes every store full-line, single-writer, single-shot:
//   P1 (1024 thr, 8192 px): LDS histogram over 1024 bins -> Hillis-Steele
//       scan -> LDS scatter (records bin-sorted in LDS) -> per-bin BURST
//       write, runs padded to 8 recs = 64 B (block-exclusive lines; padding
//       filled with depth=+inf dummies so lines are fully written).
//       pidx (slab slot per pixel) is written coalesced INTO out.
//   P2: per-bin 66x66 LDS tile; records carry depth; vis -> separate dense
//       array (coalesced full-line writes; slab stays clean, no writeback).
//   P3: reads pidx from out (coalesced), gathers vis (L2/L3-resident, just
//       written), overwrites out coalesced NT. SENT (overflow) -> recompute.
// Host runs ceil(8/nb) rounds sized to ws (nb=2 fits the proven >=50.3 MB).

#define SHARPNESS 1000.0f
#define BIAS 0.008f
#define S2LOG2E 1442.6950408889634f    // 1000 * log2(e)

#define S_IMG   2048
#define NBATCH  8
#define HWK     (1 << 20)
#define TSH     6                      // 64x64 tiles
#define TPS     32
#define BPB     (TPS * TPS)            // 1024 bins per batch
#define CAP     1792                   // padded mean ~1446, sigma ~45 -> +7.7σ
#define RPT     7                      // CAP / 256
#define STW     66                     // staged tile width (64 + halo)
#define PXB     8192                   // pixels per P1 block
#define P1T     1024
#define PPT     (PXB / P1T)            // 8 px/thread
#define SENT    0xFFFFFFFFu

typedef int      i4v __attribute__((ext_vector_type(4)));
typedef float    f2v __attribute__((ext_vector_type(2)));
typedef float    f4v __attribute__((ext_vector_type(4)));
typedef unsigned u2v __attribute__((ext_vector_type(2)));
typedef unsigned u4v __attribute__((ext_vector_type(4)));

__device__ __forceinline__ float sigf(float bb, float a) {
    const float t = (a - bb) * S2LOG2E;            // keep 2-op form: bit-stable
    return __builtin_amdgcn_rcpf(1.0f + exp2f(t));
}

// ---------------- Pass 1: LDS-sorted binning, burst full-line writes ----------------
__global__ __launch_bounds__(P1T, 2) void p1_bin(
    const int* __restrict__ xy_raw, const float* __restrict__ depth,
    u2v* __restrict__ slab, float* __restrict__ out /* pidx dest */,
    unsigned* __restrict__ gcur, int b0)
{
    __shared__ u2v      srec[PXB];     // 64 KB bin-sorted records
    __shared__ unsigned scn[BPB];      // hist -> inclusive scan -> cursor
    __shared__ unsigned lbase[BPB];    // exclusive local prefix
    __shared__ unsigned gbse[BPB];     // global run base (padded alloc)

    const int blk = blockIdx.x;
    const int bl  = blk >> 7;          // round-local batch (128 blocks each)
    const int sub = blk & 127;
    const int tid = threadIdx.x;
    scn[tid] = 0;
    __syncthreads();

    const size_t pb_g = (size_t)(b0 + bl) * HWK + (size_t)sub * PXB;
    const i4v* xq = (const i4v*)xy_raw + pb_g / 2;     // 2 px per 16B
    const f2v* dq = (const f2v*)depth  + pb_g / 2;     // 2 px per 8B

    unsigned pk[PPT]; float dd[PPT];
#pragma unroll
    for (int j = 0; j < PPT / 2; ++j) {
        const i4v q = __builtin_nontemporal_load(&xq[j * P1T + tid]);
        const f2v d = __builtin_nontemporal_load(&dq[j * P1T + tid]);
        pk[2 * j]     = (unsigned)q.x | ((unsigned)q.y << 11);
        pk[2 * j + 1] = (unsigned)q.z | ((unsigned)q.w << 11);
        dd[2 * j] = d.x; dd[2 * j + 1] = d.y;
        atomicAdd(&scn[((q.y >> TSH) << 5) | (q.x >> TSH)], 1u);
        atomicAdd(&scn[((q.w >> TSH) << 5) | (q.z >> TSH)], 1u);
    }
    __syncthreads();

    const unsigned creg = scn[tid];    // my bin's count
    // Hillis-Steele inclusive scan over 1024 bins (in place)
    for (int ofs = 1; ofs < BPB; ofs <<= 1) {
        const unsigned u = (tid >= ofs) ? scn[tid - ofs] : 0u;
        __syncthreads();
        scn[tid] += u;
        __syncthreads();
    }
    const unsigned lb = scn[tid] - creg;
    lbase[tid] = lb;
    gbse[tid]  = atomicAdd(&gcur[bl * BPB + tid], (creg + 7u) & ~7u);
    scn[tid]   = lb;                   // becomes the scatter cursor
    __syncthreads();

    // scatter into LDS (bin-sorted); emit pidx coalesced into out
    u2v* px2 = (u2v*)(out + pb_g);
#pragma unroll
    for (int j = 0; j < PPT / 2; ++j) {
        u2v pi;
#pragma unroll
        for (int e = 0; e < 2; ++e) {
            const unsigned w = pk[2 * j + e];
            const int x = (int)(w & 0x7FFu), y = (int)(w >> 11);
            const int bn = ((y >> TSH) << 5) | (x >> TSH);
            const unsigned r = atomicAdd(&scn[bn], 1u);
            u2v rec;
            rec.x = (unsigned)(x & 63) | ((unsigned)(y & 63) << 6);
            rec.y = __float_as_uint(dd[2 * j + e]);
            srec[r] = rec;
            const unsigned pos = gbse[bn] + (r - lbase[bn]);
            const unsigned slot = (pos < CAP)
                ? (unsigned)(bl * BPB + bn) * CAP + pos : SENT;
            if (e == 0) pi.x = slot; else pi.y = slot;
        }
        px2[j * P1T + tid] = pi;
    }
    __syncthreads();

    // burst-write runs: wave w -> bins [64w, 64w+64); 64B-aligned, fully written
    const int wid = tid >> 6, lane = tid & 63;
    u2v* slb = slab + (size_t)bl * BPB * CAP;
    for (int bn = wid * 64; bn < wid * 64 + 64; ++bn) {
        const int c   = (int)(scn[bn] - lbase[bn]);
        const int len = (c + 7) & ~7;
        const int src = (int)lbase[bn];
        const int gp  = (int)gbse[bn];
        u2v* dst = slb + (size_t)bn * CAP;
        for (int k = lane; k < len; k += 64) {
            const int pos = gp + k;
            if (pos < CAP) {
                u2v r;
                if (k < c) r = srec[src + k];
                else { r.x = 0u; r.y = 0x7F800000u; }  // +inf depth -> vis 0
                dst[pos] = r;
            }
        }
    }
}

// ---------------- Pass 2: LDS tile, vis to dense array ----------------
__global__ __launch_bounds__(256, 8) void p2_tile(
    const float* __restrict__ zbuf, const u2v* __restrict__ slab,
    float* __restrict__ vis, const unsigned* __restrict__ gcur, int b0)
{
    __shared__ float zt[STW * STW];                // 17.4 KB -> 8 blocks/CU
    const int gb  = blockIdx.x;                    // round-local bin
    const int tid = threadIdx.x;
    const int bl  = gb >> 10;
    const int t   = gb & (BPB - 1);
    const int tx  = t & 31, ty = t >> 5;
    const float* zb = zbuf + (size_t)(b0 + bl) * ((size_t)S_IMG * S_IMG);
    const int x0 = tx * 64 - 1, y0 = ty * 64 - 1;

    const int n   = min((int)gcur[gb], CAP);
    const int nc  = n - 1;
    const int ncc = max(nc, 0);
    const u2v* sl = slab + (size_t)gb * CAP;

    u2v Rc[RPT];                                   // preload records early
#pragma unroll
    for (int j = 0; j < RPT; ++j)
        Rc[j] = sl[min(j * 256 + tid, ncc)];

    for (int i = tid; i < STW * STW; i += 256) {
        const int r  = i / STW, c = i - r * STW;
        const int gy = min(max(y0 + r, 0), S_IMG - 1);
        const int gx = min(max(x0 + c, 0), S_IMG - 1);
        zt[i] = zb[(size_t)gy * S_IMG + gx];       // zbuf read ONCE, coalesced
    }
    __syncthreads();

    float* vb = vis + (size_t)gb * CAP;
#pragma unroll
    for (int j = 0; j < RPT; ++j) {
        const unsigned w = Rc[j].x;
        const float a  = __uint_as_float(Rc[j].y) - BIAS;
        const float* p = zt + (int)((w >> 6) & 63u) * STW + (int)(w & 63u);
        const float v =
              sigf(p[0],           a) + sigf(p[1],           a) + sigf(p[2],           a)
            + sigf(p[STW],         a) + sigf(p[STW + 1],     a) + sigf(p[STW + 2],     a)
            + sigf(p[2 * STW],     a) + sigf(p[2 * STW + 1], a) + sigf(p[2 * STW + 2], a);
        const int k = j * 256 + tid;
        if (k <= nc) vb[k] = v * (1.0f / 9.0f);    // dense coalesced write
    }
}

// ---------------- Pass 3: pidx from out -> gather vis -> overwrite out ----------------
__global__ __launch_bounds__(256) void p3_out(
    const float* __restrict__ visf, float* __restrict__ out,
    const float* __restrict__ zbuf, const float* __restrict__ depth,
    const int* __restrict__ xy_raw, int b0)
{
    const int tid = threadIdx.x;
    const size_t pxbase = (size_t)b0 * HWK + (size_t)blockIdx.x * 4096;
    const u4v* px4 = (const u4v*)(out + pxbase);

    u4v P[4];
#pragma unroll
    for (int j = 0; j < 4; ++j)
        P[j] = px4[j * 256 + tid];                 // pidx (written by P1)

    f4v V[4];
#pragma unroll
    for (int j = 0; j < 4; ++j) {
#pragma unroll
        for (int e = 0; e < 4; ++e) {
            const unsigned pi = P[j][e];
            float v;
            if (pi != SENT) {
                v = visf[pi];                      // L2/L3-resident vis
            } else {                               // overflow: recompute (rare)
                const size_t il = pxbase + (size_t)(j * 256 + tid) * 4 + e;
                const int batch = (int)(il >> 20);
                const float a = depth[il] - BIAS;
                const int x = xy_raw[2 * il], y = xy_raw[2 * il + 1];
                const float* zbb = zbuf + (size_t)batch * ((size_t)S_IMG * S_IMG);
                float vv = 0.0f;
                for (int ii = -1; ii <= 1; ++ii) {
                    const int yi = min(max(y + ii, 0), S_IMG - 1);
                    const float* row = zbb + (size_t)yi * S_IMG;
                    for (int jj = -1; jj <= 1; ++jj)
                        vv += sigf(row[min(max(x + jj, 0), S_IMG - 1)], a);
                }
                v = vv * (1.0f / 9.0f);
            }
            V[j][e] = v;
        }
    }

    f4v* o4 = (f4v*)(out + pxbase);                // same thread, same addrs
#pragma unroll
    for (int j = 0; j < 4; ++j)
        __builtin_nontemporal_store(V[j], &o4[j * 256 + tid]);
}

// ---------------- fallback: direct kernel ----------------
__global__ __launch_bounds__(256) void pcf_shadow_generic(
    const float* __restrict__ zbuf, const float* __restrict__ depth_z,
    const int2* __restrict__ xy, const int* __restrict__ image_size_p,
    float* __restrict__ out, int total, int zbuf_elems)
{
    const int i = blockIdx.x * blockDim.x + threadIdx.x;
    if (i >= total) return;
    const int S  = *image_size_p;
    const int SS = S * S;
    const int N  = zbuf_elems / SS;
    const int hwk = total / N;
    const int b   = i / hwk;
    const float a = depth_z[i] - BIAS;
    const int2 p  = xy[i];
    const float* base = zbuf + (size_t)b * (size_t)SS;
    float vis = 0.0f;
#pragma unroll
    for (int ii = -1; ii <= 1; ++ii) {
        const int yi = min(max(p.y + ii, 0), S - 1);
        const float* row = base + (size_t)yi * (size_t)S;
#pragma unroll
        for (int jj = -1; jj <= 1; ++jj) {
            const int xi = min(max(p.x + jj, 0), S - 1);
            vis += 1.0f / (1.0f + __expf((a - row[xi]) * SHARPNESS));
        }
    }
    out[i] = vis * (1.0f / 9.0f);
}

extern "C" void kernel_launch(void* const* d_in, const int* in_sizes, int n_in,
                              void* d_out, int out_size, void* d_ws, size_t ws_size,
                              hipStream_t stream) {
    const float* zbuf     = (const float*)d_in[0];
    const float* depth_z  = (const float*)d_in[1];
    const int*   xy_raw   = (const int*)d_in[2];
    const int*   img_size = (const int*)d_in[3];
    float*       out      = (float*)d_out;

    const int zbuf_elems = in_sizes[0];   // N*S*S
    const int total      = in_sizes[1];   // N*H*W*K

    if (zbuf_elems == NBATCH * S_IMG * S_IMG && total == NBATCH * HWK) {
        const size_t slab_pb = (size_t)BPB * CAP * 8ull;   // 14.68 MB
        const size_t vis_pb  = (size_t)BPB * CAP * 4ull;   //  7.34 MB
        const size_t per_b   = slab_pb + vis_pb + (size_t)BPB * 4ull;  // ~22 MB
        int nb = 0;
        if      (ws_size >= 8 * per_b) nb = 8;
        else if (ws_size >= 4 * per_b) nb = 4;
        else if (ws_size >= 2 * per_b) nb = 2;    // 44.1 MB <= proven 50.3
        else if (ws_size >= 1 * per_b) nb = 1;

        if (nb) {
            u2v*      slab = (u2v*)d_ws;
            float*    vis  = (float*)((char*)d_ws + (size_t)nb * slab_pb);
            unsigned* gcur = (unsigned*)((char*)d_ws + (size_t)nb * (slab_pb + vis_pb));
            for (int b0 = 0; b0 < NBATCH; b0 += nb) {
                hipMemsetAsync(gcur, 0, (size_t)nb * BPB * 4ull, stream);
                p1_bin <<<nb * 128, P1T, 0, stream>>>(xy_raw, depth_z, slab, out, gcur, b0);
                p2_tile<<<nb * BPB, 256, 0, stream>>>(zbuf, slab, vis, gcur, b0);
                p3_out <<<nb * 256, 256, 0, stream>>>(vis, out, zbuf, depth_z, xy_raw, b0);
            }
            return;
        }
    }
    const int block = 256;
    const int grid  = (total + block - 1) / block;
    pcf_shadow_generic<<<grid, block, 0, stream>>>(zbuf, depth_z, (const int2*)xy_raw,
                                                   img_size, out, total, zbuf_elems);
}